// Round 4
// baseline (871.715 us; speedup 1.0000x reference)
//
#include <hip/hip_runtime.h>
#include <math.h>

typedef unsigned short ushort_t;
typedef __attribute__((ext_vector_type(8))) short short8;   // 8 bf16 = 4 VGPRs
typedef __attribute__((ext_vector_type(4))) float floatx4;  // MFMA accumulator

// Problem constants
constexpr int NT = 4096;     // tokens
constexpr int H  = 1024;     // hidden
constexpr int V  = 50257;    // vocab
constexpr int CUT1 = 20000;
constexpr int CUT2 = 40000;

// MFMA-path geometry
constexpr int NPAD_TOK = 4224;            // 4096 + 128 pad rows (zeroed)
constexpr int NPAD_COL = 50432;           // covers last col tile
constexpr int CT0 = 157, CT1 = 157, CT2 = 81;
constexpr int CT_TOTAL = CT0 + CT1 + CT2;      // 395 col tiles
constexpr int MAX_TTILES = 32;                 // worst case: all tokens one cluster

// fp32 fallback geometry (round-1 path, used only if ws too small)
constexpr int FB_TILES0 = (20000 + 63) / 64;
constexpr int FB_TILES1 = (20000 + 63) / 64;
constexpr int FB_TILES2 = (V - 40000 + 63) / 64;
constexpr int FB_TOTAL = FB_TILES0 + FB_TILES1 + FB_TILES2;

// gfx9 s_waitcnt SIMM16: vmcnt[3:0]@0, expcnt@4, lgkmcnt@8, vmcnt[5:4]@14
#define WAITCNT_VM8 0x0F78  // vmcnt(8), lgkmcnt/expcnt unconstrained
#define WAITCNT_VM0 0x0F70  // vmcnt(0)

__device__ __forceinline__ ushort_t f2bf(float f) {
  unsigned int u = __float_as_uint(f);
  u = (u + 0x7FFFu + ((u >> 16) & 1u)) >> 16;  // round-to-nearest-even
  return (ushort_t)u;
}
__device__ __forceinline__ float bf2f(ushort_t b) {
  return __uint_as_float(((unsigned int)b) << 16);
}
__device__ __forceinline__ void gl_lds16(const void* g, void* l) {
  __builtin_amdgcn_global_load_lds(
      (const __attribute__((address_space(1))) void*)g,
      (__attribute__((address_space(3))) void*)l, 16, 0, 0);
}

// ---------------------------------------------------------------------------
// Kernel 1: classify tokens, build perm (ballot + exact prefix, atomic-free,
// deterministic), zero sumexp.
// ---------------------------------------------------------------------------
__global__ __launch_bounds__(1024) void setup_kernel(
    const int* __restrict__ y, int* __restrict__ offsets,
    int* __restrict__ perm, float* __restrict__ sumexp) {
  __shared__ int wcnt[16][3];
  __shared__ int wstart[16][3];
  int tid = threadIdx.x, lane = tid & 63, wid = tid >> 6;
  for (int i = tid; i < NT; i += 1024) sumexp[i] = 0.f;

  int kc[4];
  unsigned long long msk[4][3];
  int cw0 = 0, cw1 = 0, cw2 = 0;
  #pragma unroll
  for (int e = 0; e < 4; e++) {
    int v = y[tid + e * 1024];
    kc[e] = (v >= CUT1) + (v >= CUT2);
    msk[e][0] = __ballot(kc[e] == 0);
    msk[e][1] = __ballot(kc[e] == 1);
    msk[e][2] = __ballot(kc[e] == 2);
    cw0 += __popcll(msk[e][0]);
    cw1 += __popcll(msk[e][1]);
    cw2 += __popcll(msk[e][2]);
  }
  if (lane == 0) { wcnt[wid][0] = cw0; wcnt[wid][1] = cw1; wcnt[wid][2] = cw2; }
  __syncthreads();
  if (tid == 0) {
    int t0 = 0, t1 = 0, t2 = 0;
    for (int wv = 0; wv < 16; wv++) { t0 += wcnt[wv][0]; t1 += wcnt[wv][1]; t2 += wcnt[wv][2]; }
    offsets[0] = 0; offsets[1] = t0; offsets[2] = t0 + t1; offsets[3] = NT;
    int c0 = 0, c1 = t0, c2 = t0 + t1;
    for (int wv = 0; wv < 16; wv++) {
      wstart[wv][0] = c0; c0 += wcnt[wv][0];
      wstart[wv][1] = c1; c1 += wcnt[wv][1];
      wstart[wv][2] = c2; c2 += wcnt[wv][2];
    }
  }
  __syncthreads();
  int r0 = wstart[wid][0], r1 = wstart[wid][1], r2 = wstart[wid][2];
  unsigned long long below = (1ull << lane) - 1ull;
  #pragma unroll
  for (int e = 0; e < 4; e++) {
    int t = tid + e * 1024;
    int c = kc[e];
    int start = (c == 0) ? r0 : ((c == 1) ? r1 : r2);
    perm[start + __popcll(msk[e][c] & below)] = t;
    r0 += __popcll(msk[e][0]);
    r1 += __popcll(msk[e][1]);
    r2 += __popcll(msk[e][2]);
  }
}

// ---------------------------------------------------------------------------
// Kernel 2: gather x into perm order as bf16 (float4 -> ushort4); zero pad.
// ---------------------------------------------------------------------------
__global__ __launch_bounds__(256) void gather_kernel(
    const float* __restrict__ x, const int* __restrict__ perm,
    ushort_t* __restrict__ xb) {
  int p = blockIdx.x;
  int src = (p < NT) ? perm[p] : -1;
  int k = threadIdx.x * 4;
  ushort4 o;
  if (src >= 0) {
    float4 v = *(const float4*)&x[(size_t)src * H + k];
    o.x = f2bf(v.x); o.y = f2bf(v.y); o.z = f2bf(v.z); o.w = f2bf(v.w);
  } else {
    o.x = 0; o.y = 0; o.z = 0; o.w = 0;
  }
  *(ushort4*)&xb[(size_t)p * H + k] = o;
}

// ---------------------------------------------------------------------------
// Kernel 3: transpose+convert logits [H][V] fp32 -> lt [NPAD_COL][H] bf16.
// 64k x 128col tiles; float4 loads, ushort4 stores; pad cols zero-filled.
// ---------------------------------------------------------------------------
__global__ __launch_bounds__(256) void transpose_kernel(
    const float* __restrict__ logits, ushort_t* __restrict__ lt) {
  __shared__ float ts[64][133];  // +5 pad: 2-way (free) conflicts on read side
  int col0 = blockIdx.x * 128, k0 = blockIdx.y * 64;
  int tid = threadIdx.x;
  #pragma unroll
  for (int e = 0; e < 8; e++) {
    int i = e * 256 + tid;       // 0..2047
    int r = i >> 5, q = i & 31;  // row 0..63, float4-slot 0..31
    int col = col0 + q * 4;
    float4 v;
    if (col + 3 < V) {
      v = *(const float4*)&logits[(size_t)(k0 + r) * V + col];
    } else {
      v.x = (col + 0 < V) ? logits[(size_t)(k0 + r) * V + col + 0] : 0.f;
      v.y = (col + 1 < V) ? logits[(size_t)(k0 + r) * V + col + 1] : 0.f;
      v.z = (col + 2 < V) ? logits[(size_t)(k0 + r) * V + col + 2] : 0.f;
      v.w = (col + 3 < V) ? logits[(size_t)(k0 + r) * V + col + 3] : 0.f;
    }
    ts[r][4 * q + 0] = v.x;
    ts[r][4 * q + 1] = v.y;
    ts[r][4 * q + 2] = v.z;
    ts[r][4 * q + 3] = v.w;
  }
  __syncthreads();
  #pragma unroll
  for (int e = 0; e < 8; e++) {
    int i = e * 256 + tid;
    int col = i >> 4, kq = i & 15;  // col 0..127, k-quad 0..15
    ushort4 o;
    o.x = f2bf(ts[4 * kq + 0][col]);
    o.y = f2bf(ts[4 * kq + 1][col]);
    o.z = f2bf(ts[4 * kq + 2][col]);
    o.w = f2bf(ts[4 * kq + 3][col]);
    *(ushort4*)&lt[(size_t)(col0 + col) * H + k0 + 4 * kq] = o;
  }
}

// ---------------------------------------------------------------------------
// Kernel 4: cluster-head log-softmax (fp32) + target logit (bf16 lt row).
// ---------------------------------------------------------------------------
__global__ __launch_bounds__(256) void head_kernel(
    const float* __restrict__ x, const int* __restrict__ y,
    const float* __restrict__ Wc, const ushort_t* __restrict__ lt,
    float* __restrict__ neg_cll, float* __restrict__ z_tgt) {
  int tid = threadIdx.x;
  int lane = tid & 63;
  int token = blockIdx.x * 4 + (tid >> 6);
  int yv = y[token];
  const float* xp = x + (size_t)token * H;
  const ushort_t* lp = lt + (size_t)yv * H;
  float c0 = 0.f, c1 = 0.f, c2 = 0.f, zt = 0.f;
  #pragma unroll
  for (int j = 0; j < 16; j++) {
    int h = lane + j * 64;
    float xv = xp[h];
    c0 = fmaf(xv, Wc[h], c0);
    c1 = fmaf(xv, Wc[H + h], c1);
    c2 = fmaf(xv, Wc[2 * H + h], c2);
    zt = fmaf(xv, bf2f(lp[h]), zt);
  }
  #pragma unroll
  for (int d = 32; d; d >>= 1) {
    c0 += __shfl_down(c0, d);
    c1 += __shfl_down(c1, d);
    c2 += __shfl_down(c2, d);
    zt += __shfl_down(zt, d);
  }
  if (lane == 0) {
    float m = fmaxf(c0, fmaxf(c1, c2));
    float lse = m + logf(expf(c0 - m) + expf(c1 - m) + expf(c2 - m));
    int k = (yv >= CUT1) + (yv >= CUT2);
    float ck = (k == 0) ? c0 : ((k == 1) ? c1 : c2);
    neg_cll[token] = lse - ck;
    z_tgt[token] = zt;
  }
}

// ---------------------------------------------------------------------------
// Kernel 5: MFMA main loop. 128x128 tile, BK=64, DOUBLE-BUFFERED LDS with
// raw s_barrier + s_waitcnt vmcnt(8) (AITER-style: loads stay in flight
// across barriers; only the previous tile's loads are awaited).
// Grid: x=token-tile (fast), y=col-tile -> consecutive blocks share one
// lt slice (L2-resident) for locality. XOR chunk swizzle as in R3.
// ---------------------------------------------------------------------------
__global__ __launch_bounds__(256) void mfma_kernel(
    const ushort_t* __restrict__ xb, const ushort_t* __restrict__ lt,
    const int* __restrict__ offsets, float* __restrict__ sumexp) {
  int ct = blockIdx.y;
  int c, col0, colEnd;
  if (ct < CT0)            { c = 0; col0 = ct * 128;                      colEnd = CUT1; }
  else if (ct < CT0 + CT1) { c = 1; col0 = CUT1 + (ct - CT0) * 128;       colEnd = CUT2; }
  else                     { c = 2; col0 = CUT2 + (ct - CT0 - CT1) * 128; colEnd = V; }

  int t0 = offsets[c] + blockIdx.x * 128;
  int tEnd = offsets[c + 1];
  if (t0 >= tEnd) return;  // uniform across block: no barrier divergence

  __shared__ __align__(16) ushort_t xs[2][128 * 64];  // 2 x 16 KB
  __shared__ __align__(16) ushort_t ls[2][128 * 64];  // 2 x 16 KB

  int tid = threadIdx.x;
  int lane = tid & 63;
  int w = tid >> 6;                 // wave 0..3
  int wm = w >> 1, wn = w & 1;      // 2x2 wave grid
  int m_in = lane & 15, quad = lane >> 4;

  // staging: wave w stages rows [w*32, w*32+32), 4 calls of 8 rows x 128 B.
  // lane = srow*8 + sc; LDS slot sc receives global chunk sc ^ srow.
  int srow = lane >> 3;
  int sc = lane & 7;
  int gchunk = sc ^ srow;
  const ushort_t* ga[4];
  const ushort_t* gb[4];
  int lofs[4];
  #pragma unroll
  for (int cc = 0; cc < 4; cc++) {
    int r0 = w * 32 + cc * 8;
    ga[cc] = xb + (size_t)(t0 + r0 + srow) * H + gchunk * 8;
    gb[cc] = lt + (size_t)(col0 + r0 + srow) * H + gchunk * 8;
    lofs[cc] = r0 * 64;
  }

  floatx4 acc[4][4];
  #pragma unroll
  for (int i = 0; i < 4; i++)
    #pragma unroll
    for (int j = 0; j < 4; j++)
      acc[i][j] = (floatx4){0.f, 0.f, 0.f, 0.f};

  // prologue: stage k-tile 0 into buffer 0 (8 loads in flight)
  #pragma unroll
  for (int cc = 0; cc < 4; cc++) {
    gl_lds16(ga[cc], &xs[0][lofs[cc]]);
    gl_lds16(gb[cc], &ls[0][lofs[cc]]);
    ga[cc] += 64; gb[cc] += 64;
  }

  for (int it = 0; it < 16; ++it) {
    int cur = it & 1;
    if (it < 15) {
      int nxt = cur ^ 1;
      // issue next tile's loads (target buffer was consumed at it-1; WAR
      // protected by the trailing barrier of it-1)
      #pragma unroll
      for (int cc = 0; cc < 4; cc++) {
        gl_lds16(ga[cc], &xs[nxt][lofs[cc]]);
        gl_lds16(gb[cc], &ls[nxt][lofs[cc]]);
        ga[cc] += 64; gb[cc] += 64;
      }
      __builtin_amdgcn_s_waitcnt(WAITCNT_VM8);  // current tile's loads done
    } else {
      __builtin_amdgcn_s_waitcnt(WAITCNT_VM0);  // drain last tile
    }
    __builtin_amdgcn_s_barrier();  // cross-wave RAW: everyone's loads landed

    #pragma unroll
    for (int h = 0; h < 2; h++) {  // two K=32 halves of the BK=64 tile
      short8 af[4], bf[4];
      #pragma unroll
      for (int i = 0; i < 4; i++) {
        int row = wm * 64 + i * 16 + m_in;
        int slot = (h * 4 + quad) ^ (row & 7);
        af[i] = *(const short8*)&xs[cur][row * 64 + slot * 8];
      }
      #pragma unroll
      for (int j = 0; j < 4; j++) {
        int row = wn * 64 + j * 16 + m_in;
        int slot = (h * 4 + quad) ^ (row & 7);
        bf[j] = *(const short8*)&ls[cur][row * 64 + slot * 8];
      }
      #pragma unroll
      for (int i = 0; i < 4; i++)
        #pragma unroll
        for (int j = 0; j < 4; j++)
          acc[i][j] = __builtin_amdgcn_mfma_f32_16x16x32_bf16(af[i], bf[j], acc[i][j], 0, 0, 0);
    }
    __builtin_amdgcn_s_barrier();  // WAR: reads of buf[cur] complete
  }

  // Epilogue: C/D layout col=lane&15, row=quad*4+reg (verified m89/m91).
  #pragma unroll
  for (int i = 0; i < 4; i++) {
    #pragma unroll
    for (int r = 0; r < 4; r++) {
      float s = 0.f;
      #pragma unroll
      for (int j = 0; j < 4; j++) {
        int col = col0 + wn * 64 + j * 16 + m_in;
        if (col < colEnd) s += __expf(acc[i][j][r]);
      }
      s += __shfl_down(s, 8, 16);
      s += __shfl_down(s, 4, 16);
      s += __shfl_down(s, 2, 16);
      s += __shfl_down(s, 1, 16);
      if (m_in == 0) {
        int rowt = wm * 64 + i * 16 + quad * 4 + r;
        if (t0 + rowt < tEnd) atomicAdd(&sumexp[t0 + rowt], s);
      }
    }
  }
}

// ---------------------------------------------------------------------------
// Kernel 6: finalize. sumexp is perm-indexed; scatter to token order.
// ---------------------------------------------------------------------------
__global__ __launch_bounds__(256) void final_kernel(
    const int* __restrict__ perm, const float* __restrict__ neg_cll,
    const float* __restrict__ z_tgt, const float* __restrict__ sumexp,
    float* __restrict__ out) {
  int p = blockIdx.x * 256 + threadIdx.x;
  if (p < NT) {
    int t = perm[p];
    out[t] = neg_cll[t] + logf(sumexp[p]) - z_tgt[t];
  }
}

// ===========================================================================
// Round-1 fp32 fallback path (used only if ws_size is too small for lt/xb).
// ===========================================================================
__global__ __launch_bounds__(256) void head_kernel_fb(
    const float* __restrict__ x, const int* __restrict__ y,
    const float* __restrict__ Wc, const float* __restrict__ logits,
    float* __restrict__ neg_cll, float* __restrict__ z_tgt) {
  int tid = threadIdx.x;
  int lane = tid & 63;
  int token = blockIdx.x * 4 + (tid >> 6);
  int yv = y[token];
  const float* xp = x + (size_t)token * H;
  float c0 = 0.f, c1 = 0.f, c2 = 0.f, zt = 0.f;
  #pragma unroll
  for (int j = 0; j < 16; j++) {
    int h = lane + j * 64;
    float xv = xp[h];
    c0 = fmaf(xv, Wc[h], c0);
    c1 = fmaf(xv, Wc[H + h], c1);
    c2 = fmaf(xv, Wc[2 * H + h], c2);
    zt = fmaf(xv, logits[(size_t)h * V + yv], zt);
  }
  #pragma unroll
  for (int d = 32; d; d >>= 1) {
    c0 += __shfl_down(c0, d);
    c1 += __shfl_down(c1, d);
    c2 += __shfl_down(c2, d);
    zt += __shfl_down(zt, d);
  }
  if (lane == 0) {
    float m = fmaxf(c0, fmaxf(c1, c2));
    float lse = m + logf(expf(c0 - m) + expf(c1 - m) + expf(c2 - m));
    int k = (yv >= CUT1) + (yv >= CUT2);
    float ck = (k == 0) ? c0 : ((k == 1) ? c1 : c2);
    neg_cll[token] = lse - ck;
    z_tgt[token] = zt;
  }
}

__global__ __launch_bounds__(256) void main_kernel_fb(
    const float* __restrict__ x, const float* __restrict__ logits,
    const int* __restrict__ offsets, const int* __restrict__ perm,
    float* __restrict__ sumexp) {
  int ct = blockIdx.x;
  int c, lct;
  if (ct < FB_TILES0)                  { c = 0; lct = ct; }
  else if (ct < FB_TILES0 + FB_TILES1) { c = 1; lct = ct - FB_TILES0; }
  else                                 { c = 2; lct = ct - FB_TILES0 - FB_TILES1; }
  int colBase = (c == 0) ? 0 : ((c == 1) ? CUT1 : CUT2);
  int colEnd  = (c == 0) ? CUT1 : ((c == 1) ? CUT2 : V);
  int col0 = colBase + lct * 64;
  int ncols = min(64, colEnd - col0);

  int t0 = offsets[c] + blockIdx.y * 64;
  int tEnd = offsets[c + 1];
  if (t0 >= tEnd) return;
  int ntok = min(64, tEnd - t0);

  __shared__ int tok_s[64];
  __shared__ float xsf[32][68];
  __shared__ float lsm[32][68];

  int tid = threadIdx.x;
  if (tid < 64) tok_s[tid] = perm[t0 + min(tid, ntok - 1)];
  __syncthreads();

  int tg = tid >> 4;
  int cg = tid & 15;
  float acc[4][4] = {};

  for (int h0 = 0; h0 < H; h0 += 32) {
    __syncthreads();
    #pragma unroll
    for (int e = 0; e < 8; e++) {
      int elem = e * 256 + tid;
      int tt = elem >> 5, kk = elem & 31;
      xsf[kk][tt] = x[(size_t)tok_s[tt] * H + h0 + kk];
    }
    #pragma unroll
    for (int e = 0; e < 8; e++) {
      int elem = e * 256 + tid;
      int kk = elem >> 6, cc = elem & 63;
      lsm[kk][cc] = (cc < ncols) ? logits[(size_t)(h0 + kk) * V + col0 + cc] : 0.f;
    }
    __syncthreads();
    #pragma unroll
    for (int kk = 0; kk < 32; kk++) {
      float4 xv = *(const float4*)&xsf[kk][4 * tg];
      float4 lv = *(const float4*)&lsm[kk][4 * cg];
      acc[0][0] = fmaf(xv.x, lv.x, acc[0][0]);
      acc[0][1] = fmaf(xv.x, lv.y, acc[0][1]);
      acc[0][2] = fmaf(xv.x, lv.z, acc[0][2]);
      acc[0][3] = fmaf(xv.x, lv.w, acc[0][3]);
      acc[1][0] = fmaf(xv.y, lv.x, acc[1][0]);
      acc[1][1] = fmaf(xv.y, lv.y, acc[1][1]);
      acc[1][2] = fmaf(xv.y, lv.z, acc[1][2]);
      acc[1][3] = fmaf(xv.y, lv.w, acc[1][3]);
      acc[2][0] = fmaf(xv.z, lv.x, acc[2][0]);
      acc[2][1] = fmaf(xv.z, lv.y, acc[2][1]);
      acc[2][2] = fmaf(xv.z, lv.z, acc[2][2]);
      acc[2][3] = fmaf(xv.z, lv.w, acc[2][3]);
      acc[3][0] = fmaf(xv.w, lv.x, acc[3][0]);
      acc[3][1] = fmaf(xv.w, lv.y, acc[3][1]);
      acc[3][2] = fmaf(xv.w, lv.z, acc[3][2]);
      acc[3][3] = fmaf(xv.w, lv.w, acc[3][3]);
    }
  }

  float s[4];
  #pragma unroll
  for (int i = 0; i < 4; i++) {
    float v = 0.f;
    #pragma unroll
    for (int j = 0; j < 4; j++) {
      if (4 * cg + j < ncols) v += expf(acc[i][j]);
    }
    s[i] = v;
  }
  #pragma unroll
  for (int i = 0; i < 4; i++) {
    #pragma unroll
    for (int d = 8; d; d >>= 1) s[i] += __shfl_down(s[i], d, 16);
  }
  if (cg == 0) {
    #pragma unroll
    for (int i = 0; i < 4; i++) {
      int tt = 4 * tg + i;
      if (tt < ntok) atomicAdd(&sumexp[tok_s[tt]], s[i]);
    }
  }
}

__global__ __launch_bounds__(256) void final_kernel_fb(
    const float* __restrict__ neg_cll, const float* __restrict__ z_tgt,
    const float* __restrict__ sumexp, float* __restrict__ out) {
  int i = blockIdx.x * 256 + threadIdx.x;
  if (i < NT) out[i] = neg_cll[i] + logf(sumexp[i]) - z_tgt[i];
}

// ===========================================================================
extern "C" void kernel_launch(void* const* d_in, const int* in_sizes, int n_in,
                              void* d_out, int out_size, void* d_ws,
                              size_t ws_size, hipStream_t stream) {
  const float* x      = (const float*)d_in[0];
  const int*   y      = (const int*)d_in[1];
  const float* Wc     = (const float*)d_in[2];
  const float* logits = (const float*)d_in[3];
  float* out = (float*)d_out;

  char* ws = (char*)d_ws;
  int*   offsets = (int*)ws;                      // @0, 16 B
  int*   perm    = (int*)(ws + 256);              // 16 KB
  float* sumexp  = (float*)(ws + 16896);          // 16 KB (perm-order)
  float* neg_cll = (float*)(ws + 33280);          // 16 KB
  float* z_tgt   = (float*)(ws + 49664);          // 16 KB
  ushort_t* xb   = (ushort_t*)(ws + 66048);       // 4224*1024*2 B
  ushort_t* lt   = (ushort_t*)(ws + 66048 + (size_t)NPAD_TOK * H * 2);
  const size_t WS_NEED = 66048 + (size_t)NPAD_TOK * H * 2 + (size_t)NPAD_COL * H * 2;

  setup_kernel<<<1, 1024, 0, stream>>>(y, offsets, perm, sumexp);

  if (ws_size >= WS_NEED) {
    gather_kernel<<<NPAD_TOK, 256, 0, stream>>>(x, perm, xb);
    dim3 tg(NPAD_COL / 128, H / 64);
    transpose_kernel<<<tg, 256, 0, stream>>>(logits, lt);
    head_kernel<<<NT / 4, 256, 0, stream>>>(x, y, Wc, lt, neg_cll, z_tgt);
    dim3 grid(MAX_TTILES, CT_TOTAL);  // ttile-fastest: same-ct blocks adjacent
    mfma_kernel<<<grid, 256, 0, stream>>>(xb, lt, offsets, sumexp);
    final_kernel<<<NT / 256, 256, 0, stream>>>(perm, neg_cll, z_tgt, sumexp, out);
  } else {
    head_kernel_fb<<<NT / 4, 256, 0, stream>>>(x, y, Wc, logits, neg_cll, z_tgt);
    dim3 grid(FB_TOTAL, 64);
    main_kernel_fb<<<grid, 256, 0, stream>>>(x, logits, offsets, perm, sumexp);
    final_kernel_fb<<<NT / 256, 256, 0, stream>>>(neg_cll, z_tgt, sumexp, out);
  }
}

// Round 5
// 601.768 us; speedup vs baseline: 1.4486x; 1.4486x over previous
//
#include <hip/hip_runtime.h>
#include <math.h>

typedef unsigned short ushort_t;
typedef __attribute__((ext_vector_type(8))) short short8;   // 8 bf16 = 4 VGPRs
typedef __attribute__((ext_vector_type(4))) float floatx4;  // MFMA accumulator

// Problem constants
constexpr int NT = 4096;     // tokens
constexpr int H  = 1024;     // hidden
constexpr int V  = 50257;    // vocab
constexpr int CUT1 = 20000;
constexpr int CUT2 = 40000;

// MFMA-path geometry
constexpr int NPAD_TOK = 4224;            // 4096 + 128 pad rows (zeroed)
constexpr int NPAD_COL = 50432;           // covers last col tile
constexpr int CT0 = 157, CT1 = 157, CT2 = 81;
constexpr int CT_TOTAL = CT0 + CT1 + CT2;      // 395 col tiles
constexpr int MAX_TTILES = 32;                 // worst case: all tokens one cluster
constexpr int CT_GROUPS = (CT_TOTAL + 7) / 8;  // 50 ct-groups per XCD
constexpr int MFMA_GRID = 8 * CT_GROUPS * MAX_TTILES;  // 12800 blocks

// fp32 fallback geometry (round-1 path, used only if ws too small)
constexpr int FB_TILES0 = (20000 + 63) / 64;
constexpr int FB_TILES1 = (20000 + 63) / 64;
constexpr int FB_TILES2 = (V - 40000 + 63) / 64;
constexpr int FB_TOTAL = FB_TILES0 + FB_TILES1 + FB_TILES2;

__device__ __forceinline__ ushort_t f2bf(float f) {
  unsigned int u = __float_as_uint(f);
  u = (u + 0x7FFFu + ((u >> 16) & 1u)) >> 16;  // round-to-nearest-even
  return (ushort_t)u;
}
__device__ __forceinline__ float bf2f(ushort_t b) {
  return __uint_as_float(((unsigned int)b) << 16);
}
__device__ __forceinline__ void gl_lds16(const void* g, void* l) {
  __builtin_amdgcn_global_load_lds(
      (const __attribute__((address_space(1))) void*)g,
      (__attribute__((address_space(3))) void*)l, 16, 0, 0);
}

// ---------------------------------------------------------------------------
// Kernel 1: classify tokens, build perm (ballot + exact prefix, atomic-free,
// deterministic), zero sumexp.
// ---------------------------------------------------------------------------
__global__ __launch_bounds__(1024) void setup_kernel(
    const int* __restrict__ y, int* __restrict__ offsets,
    int* __restrict__ perm, float* __restrict__ sumexp) {
  __shared__ int wcnt[16][3];
  __shared__ int wstart[16][3];
  int tid = threadIdx.x, lane = tid & 63, wid = tid >> 6;
  for (int i = tid; i < NT; i += 1024) sumexp[i] = 0.f;

  int kc[4];
  unsigned long long msk[4][3];
  int cw0 = 0, cw1 = 0, cw2 = 0;
  #pragma unroll
  for (int e = 0; e < 4; e++) {
    int v = y[tid + e * 1024];
    kc[e] = (v >= CUT1) + (v >= CUT2);
    msk[e][0] = __ballot(kc[e] == 0);
    msk[e][1] = __ballot(kc[e] == 1);
    msk[e][2] = __ballot(kc[e] == 2);
    cw0 += __popcll(msk[e][0]);
    cw1 += __popcll(msk[e][1]);
    cw2 += __popcll(msk[e][2]);
  }
  if (lane == 0) { wcnt[wid][0] = cw0; wcnt[wid][1] = cw1; wcnt[wid][2] = cw2; }
  __syncthreads();
  if (tid == 0) {
    int t0 = 0, t1 = 0, t2 = 0;
    for (int wv = 0; wv < 16; wv++) { t0 += wcnt[wv][0]; t1 += wcnt[wv][1]; t2 += wcnt[wv][2]; }
    offsets[0] = 0; offsets[1] = t0; offsets[2] = t0 + t1; offsets[3] = NT;
    int c0 = 0, c1 = t0, c2 = t0 + t1;
    for (int wv = 0; wv < 16; wv++) {
      wstart[wv][0] = c0; c0 += wcnt[wv][0];
      wstart[wv][1] = c1; c1 += wcnt[wv][1];
      wstart[wv][2] = c2; c2 += wcnt[wv][2];
    }
  }
  __syncthreads();
  int r0 = wstart[wid][0], r1 = wstart[wid][1], r2 = wstart[wid][2];
  unsigned long long below = (1ull << lane) - 1ull;
  #pragma unroll
  for (int e = 0; e < 4; e++) {
    int t = tid + e * 1024;
    int c = kc[e];
    int start = (c == 0) ? r0 : ((c == 1) ? r1 : r2);
    perm[start + __popcll(msk[e][c] & below)] = t;
    r0 += __popcll(msk[e][0]);
    r1 += __popcll(msk[e][1]);
    r2 += __popcll(msk[e][2]);
  }
}

// ---------------------------------------------------------------------------
// Kernel 2: gather x into perm order as bf16 (float4 -> ushort4); zero pad.
// ---------------------------------------------------------------------------
__global__ __launch_bounds__(256) void gather_kernel(
    const float* __restrict__ x, const int* __restrict__ perm,
    ushort_t* __restrict__ xb) {
  int p = blockIdx.x;
  int src = (p < NT) ? perm[p] : -1;
  int k = threadIdx.x * 4;
  ushort4 o;
  if (src >= 0) {
    float4 v = *(const float4*)&x[(size_t)src * H + k];
    o.x = f2bf(v.x); o.y = f2bf(v.y); o.z = f2bf(v.z); o.w = f2bf(v.w);
  } else {
    o.x = 0; o.y = 0; o.z = 0; o.w = 0;
  }
  *(ushort4*)&xb[(size_t)p * H + k] = o;
}

// ---------------------------------------------------------------------------
// Kernel 3: transpose+convert logits [H][V] fp32 -> lt [NPAD_COL][H] bf16.
// 64k x 128col tiles; float4 loads, ushort4 stores. LDS pitch 129: read-side
// bank = (4*kq + col) & 31 spans all 32 banks -> conflict-free reads.
// ---------------------------------------------------------------------------
__global__ __launch_bounds__(256) void transpose_kernel(
    const float* __restrict__ logits, ushort_t* __restrict__ lt) {
  __shared__ float ts[64][129];
  int col0 = blockIdx.x * 128, k0 = blockIdx.y * 64;
  int tid = threadIdx.x;
  #pragma unroll
  for (int e = 0; e < 8; e++) {
    int i = e * 256 + tid;       // 0..2047
    int r = i >> 5, q = i & 31;  // row 0..63, float4-slot 0..31
    int col = col0 + q * 4;
    float4 v;
    if (col + 3 < V) {
      v = *(const float4*)&logits[(size_t)(k0 + r) * V + col];
    } else {
      v.x = (col + 0 < V) ? logits[(size_t)(k0 + r) * V + col + 0] : 0.f;
      v.y = (col + 1 < V) ? logits[(size_t)(k0 + r) * V + col + 1] : 0.f;
      v.z = (col + 2 < V) ? logits[(size_t)(k0 + r) * V + col + 2] : 0.f;
      v.w = (col + 3 < V) ? logits[(size_t)(k0 + r) * V + col + 3] : 0.f;
    }
    ts[r][4 * q + 0] = v.x;
    ts[r][4 * q + 1] = v.y;
    ts[r][4 * q + 2] = v.z;
    ts[r][4 * q + 3] = v.w;
  }
  __syncthreads();
  #pragma unroll
  for (int e = 0; e < 8; e++) {
    int i = e * 256 + tid;
    int col = i >> 4, kq = i & 15;  // col 0..127, k-quad 0..15
    ushort4 o;
    o.x = f2bf(ts[4 * kq + 0][col]);
    o.y = f2bf(ts[4 * kq + 1][col]);
    o.z = f2bf(ts[4 * kq + 2][col]);
    o.w = f2bf(ts[4 * kq + 3][col]);
    *(ushort4*)&lt[(size_t)(col0 + col) * H + k0 + 4 * kq] = o;
  }
}

// ---------------------------------------------------------------------------
// Kernel 4: cluster-head log-softmax (fp32) + target logit (bf16 lt row).
// ---------------------------------------------------------------------------
__global__ __launch_bounds__(256) void head_kernel(
    const float* __restrict__ x, const int* __restrict__ y,
    const float* __restrict__ Wc, const ushort_t* __restrict__ lt,
    float* __restrict__ neg_cll, float* __restrict__ z_tgt) {
  int tid = threadIdx.x;
  int lane = tid & 63;
  int token = blockIdx.x * 4 + (tid >> 6);
  int yv = y[token];
  const float* xp = x + (size_t)token * H;
  const ushort_t* lp = lt + (size_t)yv * H;
  float c0 = 0.f, c1 = 0.f, c2 = 0.f, zt = 0.f;
  #pragma unroll
  for (int j = 0; j < 16; j++) {
    int h = lane + j * 64;
    float xv = xp[h];
    c0 = fmaf(xv, Wc[h], c0);
    c1 = fmaf(xv, Wc[H + h], c1);
    c2 = fmaf(xv, Wc[2 * H + h], c2);
    zt = fmaf(xv, bf2f(lp[h]), zt);
  }
  #pragma unroll
  for (int d = 32; d; d >>= 1) {
    c0 += __shfl_down(c0, d);
    c1 += __shfl_down(c1, d);
    c2 += __shfl_down(c2, d);
    zt += __shfl_down(zt, d);
  }
  if (lane == 0) {
    float m = fmaxf(c0, fmaxf(c1, c2));
    float lse = m + logf(expf(c0 - m) + expf(c1 - m) + expf(c2 - m));
    int k = (yv >= CUT1) + (yv >= CUT2);
    float ck = (k == 0) ? c0 : ((k == 1) ? c1 : c2);
    neg_cll[token] = lse - ck;
    z_tgt[token] = zt;
  }
}

// ---------------------------------------------------------------------------
// Kernel 5: MFMA main loop. 128x128 tile, BK=64, single-buffered 32 KB LDS
// (R3 structure — proven best). XCD-AWARE 1D GRID: all token-tiles of one
// col-tile land on the same XCD (blocks dispatch round-robin id%8 across
// XCDs), so each lt col-slice (256 KB) is fetched once and stays in that
// XCD's 4 MB L2 for all its token-tile blocks. XOR chunk swizzle: LDS
// conflict-free (R3-verified: SQ_LDS_BANK_CONFLICT = 0).
// ---------------------------------------------------------------------------
__global__ __launch_bounds__(256) void mfma_kernel(
    const ushort_t* __restrict__ xb, const ushort_t* __restrict__ lt,
    const int* __restrict__ offsets, float* __restrict__ sumexp) {
  // XCD-aware decode: xcd = id%8 handles cts {xcd, xcd+8, ...}
  int id = blockIdx.x;
  int xcd = id & 7;
  int j = id >> 3;
  int ct = xcd + 8 * (j >> 5);   // ct-group per XCD
  int tt = j & 31;               // token tile within ct
  if (ct >= CT_TOTAL) return;

  int c, col0, colEnd;
  if (ct < CT0)            { c = 0; col0 = ct * 128;                      colEnd = CUT1; }
  else if (ct < CT0 + CT1) { c = 1; col0 = CUT1 + (ct - CT0) * 128;       colEnd = CUT2; }
  else                     { c = 2; col0 = CUT2 + (ct - CT0 - CT1) * 128; colEnd = V; }

  int t0 = offsets[c] + tt * 128;
  int tEnd = offsets[c + 1];
  if (t0 >= tEnd) return;  // uniform across block: no barrier divergence

  __shared__ __align__(16) ushort_t xs[128 * 64];  // [token][k] 128B rows
  __shared__ __align__(16) ushort_t ls[128 * 64];  // [col][k]   128B rows

  int tid = threadIdx.x;
  int lane = tid & 63;
  int w = tid >> 6;                 // wave 0..3
  int wm = w >> 1, wn = w & 1;      // 2x2 wave grid
  int m_in = lane & 15, quad = lane >> 4;

  // staging: wave w stages rows [w*32, w*32+32), 4 calls of 8 rows x 128 B.
  // lane = srow*8 + sc; LDS slot sc receives global chunk sc ^ srow.
  int srow = lane >> 3;
  int sc = lane & 7;
  int gchunk = sc ^ srow;
  const ushort_t* ga[4];
  const ushort_t* gb[4];
  ushort_t* la[4];
  ushort_t* lb[4];
  #pragma unroll
  for (int cc = 0; cc < 4; cc++) {
    int r0 = w * 32 + cc * 8;
    ga[cc] = xb + (size_t)(t0 + r0 + srow) * H + gchunk * 8;
    gb[cc] = lt + (size_t)(col0 + r0 + srow) * H + gchunk * 8;
    la[cc] = &xs[r0 * 64];
    lb[cc] = &ls[r0 * 64];
  }

  floatx4 acc[4][4];
  #pragma unroll
  for (int i = 0; i < 4; i++)
    #pragma unroll
    for (int jj = 0; jj < 4; jj++)
      acc[i][jj] = (floatx4){0.f, 0.f, 0.f, 0.f};

  for (int k0 = 0; k0 < H; k0 += 64) {
    __syncthreads();
    #pragma unroll
    for (int cc = 0; cc < 4; cc++) {
      gl_lds16(ga[cc], la[cc]);
      gl_lds16(gb[cc], lb[cc]);
      ga[cc] += 64; gb[cc] += 64;
    }
    __syncthreads();

    #pragma unroll
    for (int h = 0; h < 2; h++) {  // two K=32 halves of the BK=64 tile
      short8 af[4], bf[4];
      #pragma unroll
      for (int i = 0; i < 4; i++) {
        int row = wm * 64 + i * 16 + m_in;
        int slot = (h * 4 + quad) ^ (row & 7);
        af[i] = *(const short8*)&xs[row * 64 + slot * 8];
      }
      #pragma unroll
      for (int jj = 0; jj < 4; jj++) {
        int row = wn * 64 + jj * 16 + m_in;
        int slot = (h * 4 + quad) ^ (row & 7);
        bf[jj] = *(const short8*)&ls[row * 64 + slot * 8];
      }
      #pragma unroll
      for (int i = 0; i < 4; i++)
        #pragma unroll
        for (int jj = 0; jj < 4; jj++)
          acc[i][jj] = __builtin_amdgcn_mfma_f32_16x16x32_bf16(af[i], bf[jj], acc[i][jj], 0, 0, 0);
    }
  }

  // Epilogue: C/D layout col=lane&15, row=quad*4+reg (verified m89/m91).
  #pragma unroll
  for (int i = 0; i < 4; i++) {
    #pragma unroll
    for (int r = 0; r < 4; r++) {
      float s = 0.f;
      #pragma unroll
      for (int jj = 0; jj < 4; jj++) {
        int col = col0 + wn * 64 + jj * 16 + m_in;
        if (col < colEnd) s += __expf(acc[i][jj][r]);
      }
      s += __shfl_down(s, 8, 16);
      s += __shfl_down(s, 4, 16);
      s += __shfl_down(s, 2, 16);
      s += __shfl_down(s, 1, 16);
      if (m_in == 0) {
        int rowt = wm * 64 + i * 16 + quad * 4 + r;
        if (t0 + rowt < tEnd) atomicAdd(&sumexp[t0 + rowt], s);
      }
    }
  }
}

// ---------------------------------------------------------------------------
// Kernel 6: finalize. sumexp is perm-indexed; scatter to token order.
// ---------------------------------------------------------------------------
__global__ __launch_bounds__(256) void final_kernel(
    const int* __restrict__ perm, const float* __restrict__ neg_cll,
    const float* __restrict__ z_tgt, const float* __restrict__ sumexp,
    float* __restrict__ out) {
  int p = blockIdx.x * 256 + threadIdx.x;
  if (p < NT) {
    int t = perm[p];
    out[t] = neg_cll[t] + logf(sumexp[p]) - z_tgt[t];
  }
}

// ===========================================================================
// Round-1 fp32 fallback path (used only if ws_size is too small for lt/xb).
// ===========================================================================
__global__ __launch_bounds__(256) void head_kernel_fb(
    const float* __restrict__ x, const int* __restrict__ y,
    const float* __restrict__ Wc, const float* __restrict__ logits,
    float* __restrict__ neg_cll, float* __restrict__ z_tgt) {
  int tid = threadIdx.x;
  int lane = tid & 63;
  int token = blockIdx.x * 4 + (tid >> 6);
  int yv = y[token];
  const float* xp = x + (size_t)token * H;
  float c0 = 0.f, c1 = 0.f, c2 = 0.f, zt = 0.f;
  #pragma unroll
  for (int j = 0; j < 16; j++) {
    int h = lane + j * 64;
    float xv = xp[h];
    c0 = fmaf(xv, Wc[h], c0);
    c1 = fmaf(xv, Wc[H + h], c1);
    c2 = fmaf(xv, Wc[2 * H + h], c2);
    zt = fmaf(xv, logits[(size_t)h * V + yv], zt);
  }
  #pragma unroll
  for (int d = 32; d; d >>= 1) {
    c0 += __shfl_down(c0, d);
    c1 += __shfl_down(c1, d);
    c2 += __shfl_down(c2, d);
    zt += __shfl_down(zt, d);
  }
  if (lane == 0) {
    float m = fmaxf(c0, fmaxf(c1, c2));
    float lse = m + logf(expf(c0 - m) + expf(c1 - m) + expf(c2 - m));
    int k = (yv >= CUT1) + (yv >= CUT2);
    float ck = (k == 0) ? c0 : ((k == 1) ? c1 : c2);
    neg_cll[token] = lse - ck;
    z_tgt[token] = zt;
  }
}

__global__ __launch_bounds__(256) void main_kernel_fb(
    const float* __restrict__ x, const float* __restrict__ logits,
    const int* __restrict__ offsets, const int* __restrict__ perm,
    float* __restrict__ sumexp) {
  int ct = blockIdx.x;
  int c, lct;
  if (ct < FB_TILES0)                  { c = 0; lct = ct; }
  else if (ct < FB_TILES0 + FB_TILES1) { c = 1; lct = ct - FB_TILES0; }
  else                                 { c = 2; lct = ct - FB_TILES0 - FB_TILES1; }
  int colBase = (c == 0) ? 0 : ((c == 1) ? CUT1 : CUT2);
  int colEnd  = (c == 0) ? CUT1 : ((c == 1) ? CUT2 : V);
  int col0 = colBase + lct * 64;
  int ncols = min(64, colEnd - col0);

  int t0 = offsets[c] + blockIdx.y * 64;
  int tEnd = offsets[c + 1];
  if (t0 >= tEnd) return;
  int ntok = min(64, tEnd - t0);

  __shared__ int tok_s[64];
  __shared__ float xsf[32][68];
  __shared__ float lsm[32][68];

  int tid = threadIdx.x;
  if (tid < 64) tok_s[tid] = perm[t0 + min(tid, ntok - 1)];
  __syncthreads();

  int tg = tid >> 4;
  int cg = tid & 15;
  float acc[4][4] = {};

  for (int h0 = 0; h0 < H; h0 += 32) {
    __syncthreads();
    #pragma unroll
    for (int e = 0; e < 8; e++) {
      int elem = e * 256 + tid;
      int tt = elem >> 5, kk = elem & 31;
      xsf[kk][tt] = x[(size_t)tok_s[tt] * H + h0 + kk];
    }
    #pragma unroll
    for (int e = 0; e < 8; e++) {
      int elem = e * 256 + tid;
      int kk = elem >> 6, cc = elem & 63;
      lsm[kk][cc] = (cc < ncols) ? logits[(size_t)(h0 + kk) * V + col0 + cc] : 0.f;
    }
    __syncthreads();
    #pragma unroll
    for (int kk = 0; kk < 32; kk++) {
      float4 xv = *(const float4*)&xsf[kk][4 * tg];
      float4 lv = *(const float4*)&lsm[kk][4 * cg];
      acc[0][0] = fmaf(xv.x, lv.x, acc[0][0]);
      acc[0][1] = fmaf(xv.x, lv.y, acc[0][1]);
      acc[0][2] = fmaf(xv.x, lv.z, acc[0][2]);
      acc[0][3] = fmaf(xv.x, lv.w, acc[0][3]);
      acc[1][0] = fmaf(xv.y, lv.x, acc[1][0]);
      acc[1][1] = fmaf(xv.y, lv.y, acc[1][1]);
      acc[1][2] = fmaf(xv.y, lv.z, acc[1][2]);
      acc[1][3] = fmaf(xv.y, lv.w, acc[1][3]);
      acc[2][0] = fmaf(xv.z, lv.x, acc[2][0]);
      acc[2][1] = fmaf(xv.z, lv.y, acc[2][1]);
      acc[2][2] = fmaf(xv.z, lv.z, acc[2][2]);
      acc[2][3] = fmaf(xv.z, lv.w, acc[2][3]);
      acc[3][0] = fmaf(xv.w, lv.x, acc[3][0]);
      acc[3][1] = fmaf(xv.w, lv.y, acc[3][1]);
      acc[3][2] = fmaf(xv.w, lv.z, acc[3][2]);
      acc[3][3] = fmaf(xv.w, lv.w, acc[3][3]);
    }
  }

  float s[4];
  #pragma unroll
  for (int i = 0; i < 4; i++) {
    float v = 0.f;
    #pragma unroll
    for (int j = 0; j < 4; j++) {
      if (4 * cg + j < ncols) v += expf(acc[i][j]);
    }
    s[i] = v;
  }
  #pragma unroll
  for (int i = 0; i < 4; i++) {
    #pragma unroll
    for (int d = 8; d; d >>= 1) s[i] += __shfl_down(s[i], d, 16);
  }
  if (cg == 0) {
    #pragma unroll
    for (int i = 0; i < 4; i++) {
      int tt = 4 * tg + i;
      if (tt < ntok) atomicAdd(&sumexp[tok_s[tt]], s[i]);
    }
  }
}

__global__ __launch_bounds__(256) void final_kernel_fb(
    const float* __restrict__ neg_cll, const float* __restrict__ z_tgt,
    const float* __restrict__ sumexp, float* __restrict__ out) {
  int i = blockIdx.x * 256 + threadIdx.x;
  if (i < NT) out[i] = neg_cll[i] + logf(sumexp[i]) - z_tgt[i];
}

// ===========================================================================
extern "C" void kernel_launch(void* const* d_in, const int* in_sizes, int n_in,
                              void* d_out, int out_size, void* d_ws,
                              size_t ws_size, hipStream_t stream) {
  const float* x      = (const float*)d_in[0];
  const int*   y      = (const int*)d_in[1];
  const float* Wc     = (const float*)d_in[2];
  const float* logits = (const float*)d_in[3];
  float* out = (float*)d_out;

  char* ws = (char*)d_ws;
  int*   offsets = (int*)ws;                      // @0, 16 B
  int*   perm    = (int*)(ws + 256);              // 16 KB
  float* sumexp  = (float*)(ws + 16896);          // 16 KB (perm-order)
  float* neg_cll = (float*)(ws + 33280);          // 16 KB
  float* z_tgt   = (float*)(ws + 49664);          // 16 KB
  ushort_t* xb   = (ushort_t*)(ws + 66048);       // 4224*1024*2 B
  ushort_t* lt   = (ushort_t*)(ws + 66048 + (size_t)NPAD_TOK * H * 2);
  const size_t WS_NEED = 66048 + (size_t)NPAD_TOK * H * 2 + (size_t)NPAD_COL * H * 2;

  setup_kernel<<<1, 1024, 0, stream>>>(y, offsets, perm, sumexp);

  if (ws_size >= WS_NEED) {
    gather_kernel<<<NPAD_TOK, 256, 0, stream>>>(x, perm, xb);
    dim3 tg(NPAD_COL / 128, H / 64);
    transpose_kernel<<<tg, 256, 0, stream>>>(logits, lt);
    head_kernel<<<NT / 4, 256, 0, stream>>>(x, y, Wc, lt, neg_cll, z_tgt);
    mfma_kernel<<<MFMA_GRID, 256, 0, stream>>>(xb, lt, offsets, sumexp);
    final_kernel<<<NT / 256, 256, 0, stream>>>(perm, neg_cll, z_tgt, sumexp, out);
  } else {
    head_kernel_fb<<<NT / 4, 256, 0, stream>>>(x, y, Wc, logits, neg_cll, z_tgt);
    dim3 grid(FB_TOTAL, 64);
    main_kernel_fb<<<grid, 256, 0, stream>>>(x, logits, offsets, perm, sumexp);
    final_kernel_fb<<<NT / 256, 256, 0, stream>>>(neg_cll, z_tgt, sumexp, out);
  }
}